// Round 10
// baseline (194.637 us; speedup 1.0000x reference)
//
#include <hip/hip_runtime.h>

#define BATCH 16
#define CH    64
#define TLEN  200
#define NP    30
#define HID   128
#define NSEQ  (BATCH * NP)   // 480
#define HP    144            // hz row pitch in halves (288 B)
#define XP    72             // xlds per-seq row pitch in halves (144 B)
#define XGW   520            // xgb row pitch in floats (2080 B)

typedef _Float16 half8 __attribute__((ext_vector_type(8)));
typedef float    f32x4 __attribute__((ext_vector_type(4)));

// NaN/Inf-safe, clamp-free: exp->inf degrades gracefully through rcp.
__device__ __forceinline__ float sigm_fast(float x) {
    return __builtin_amdgcn_rcpf(1.0f + __expf(-x));
}
__device__ __forceinline__ float tanh_fast(float x) {
    return 1.0f - 2.0f * __builtin_amdgcn_rcpf(__expf(2.0f * x) + 1.0f);
}
__device__ __forceinline__ half8 cvt8(float4 a, float4 b) {
    return (half8){(_Float16)a.x,(_Float16)a.y,(_Float16)a.z,(_Float16)a.w,
                   (_Float16)b.x,(_Float16)b.y,(_Float16)b.z,(_Float16)b.w};
}

#define MFMA16(A,B,C) __builtin_amdgcn_mfma_f32_16x16x32_f16((A),(B),(C),0,0,0)

// ---------------------------------------------------------------------------
// Fused LSTM. 240 blocks (XCD-swizzled), 512 threads = 8 waves = 2 waves/SIMD.
// r10: attack MFMA dependent-chain latency + step-head LDS latency.
//   - split-K accumulator chains: 8 chains of depth 2 (was 4 of depth 4).
//     If dependent-MFMA latency is the hidden ~400cy/step cost (the bucket no
//     r5-r9 restructuring moved), ILP 8 covers it. One hoisted zero f32x4 is
//     the shared C-in (no per-step re-zero). Gate = chain0[0]+chain1[0]+xg.
//   - xg4 for step t+1 prefetched BEFORE the barrier (producer burst wrote it
//     >=1 barrier earlier -> race-free); its ~120cy latency rides the barrier.
//   - setprio removed (neutral r5-r9).
//   - h compact store + zero-row broadcast A-reads (r9); x fully LDS-resident,
//     zero VMEM in loop (r8); acc-major i,f,g early / o last (r7).
// ---------------------------------------------------------------------------
__global__ __launch_bounds__(512, 2) void fused_lstm(
    const float* __restrict__ x, const float* __restrict__ W_ih,
    const float* __restrict__ W_hh, const float* __restrict__ b_ih,
    const float* __restrict__ b_hh, const float* __restrict__ W_fc,
    const float* __restrict__ b_fc, float* __restrict__ out)
{
    const int tid = threadIdx.x;
    const int w  = tid >> 6;     // wave 0..7 -> owns gate sub-cols 16w+lr
    const int l  = tid & 63;
    const int lr = l & 15;
    const int lq = l >> 4;

    // XCD-chunked swizzle: XCD c gets pairs c*30..c*30+29 (= 2 full batches)
    const int blk  = blockIdx.x;
    const int pair = (blk & 7) * 30 + (blk >> 3);
    const int n0 = pair * 2;
    const int b0 = n0 / NP;
    const int p0 = n0 % NP;      // even -> both seqs share b0

    __shared__ __align__(16) _Float16 hz[5][HP];         // 1440 B; h compact + zero row
    __shared__ __align__(16) _Float16 xlds[TLEN][2][XP]; // 57600 B; ALL x, f16
    __shared__ __align__(16) float    xgb[2][16 * XGW];  // 66560 B; xg+bias, f32 C-layout

    // ---- W fragments in registers (loaded once) ----
    half8 bhh[4][4];   // W_hh, gate-type T, K-frag kt (K=128)
    half8 bih[4][2];   // W_ih, gate-type T, K-frag j  (K=64)
    float biasx[4];
#pragma unroll
    for (int T = 0; T < 4; ++T) {
        const int g = 128*T + 16*w + lr;
        const float* rh = W_hh + (size_t)g * HID;
        const float* ri = W_ih + (size_t)g * CH;
#pragma unroll
        for (int kt = 0; kt < 4; ++kt) {
            const int k0 = 32*kt + 8*lq;
            bhh[T][kt] = cvt8(*(const float4*)(rh + k0), *(const float4*)(rh + k0 + 4));
        }
#pragma unroll
        for (int j = 0; j < 2; ++j) {
            const int k0 = 32*j + 8*lq;
            bih[T][j] = cvt8(*(const float4*)(ri + k0), *(const float4*)(ri + k0 + 4));
        }
        biasx[T] = b_ih[g] + b_hh[g];
    }

    // zero hz: rows 0-3 = h_0 = 0; row 4 = permanent zero row (never written)
    if (tid < (5 * HP) / 2) ((unsigned*)hz)[tid] = 0u;

    // ---- prologue: stage ALL x for both seqs into LDS (one-time gather).
    for (int e = tid; e < CH * TLEN; e += 512) {
        const int t = e % TLEN, c = e / TLEN;
        const float* src = x + ((size_t)(b0 * CH + c) * TLEN + t) * NP + p0;
        float2 v = *(const float2*)src;
        xlds[t][0][c] = (_Float16)v.x;
        xlds[t][1][c] = (_Float16)v.y;
    }
    float cst = 0.f;                      // c-state: valid in lanes l<32
    const int hcol = 16*w + lr;
    // A-frag source rows: lr==0 -> seq0 row, lr==4 -> seq1 row, else ZERO row.
    const int hrow0 = (lr == 0) ? 0 : (lr == 4) ? 1 : 4;   // buf 0
    const int hrow1 = (lr == 0) ? 2 : (lr == 4) ? 3 : 4;   // buf 1
    const _Float16* hpA = &hz[hrow0][8 * lq];
    const _Float16* hpB = &hz[hrow1][8 * lq];
    __syncthreads();                      // hz + xlds resident

    // per-period xg GEMM from resident xlds (rows t=8P..8P+7, both seqs).
#define XG_BURST(P, TB) {                                                         \
        const _Float16* xr_ = &xlds[8*(P) + (lr >> 1)][lr & 1][8*lq];             \
        half8 xf0_ = *(const half8*)xr_;                                          \
        half8 xf1_ = *(const half8*)(xr_ + 32);                                   \
        f32x4 g0_ = {biasx[0], biasx[0], biasx[0], biasx[0]};                     \
        f32x4 g1_ = {biasx[1], biasx[1], biasx[1], biasx[1]};                     \
        f32x4 g2_ = {biasx[2], biasx[2], biasx[2], biasx[2]};                     \
        f32x4 g3_ = {biasx[3], biasx[3], biasx[3], biasx[3]};                     \
        g0_ = MFMA16(xf0_, bih[0][0], g0_); g0_ = MFMA16(xf1_, bih[0][1], g0_);   \
        g1_ = MFMA16(xf0_, bih[1][0], g1_); g1_ = MFMA16(xf1_, bih[1][1], g1_);   \
        g2_ = MFMA16(xf0_, bih[2][0], g2_); g2_ = MFMA16(xf1_, bih[2][1], g2_);   \
        g3_ = MFMA16(xf0_, bih[3][0], g3_); g3_ = MFMA16(xf1_, bih[3][1], g3_);   \
        _Pragma("unroll") for (int r_ = 0; r_ < 4; ++r_) {                        \
            float* dst_ = &xgb[TB][(4*lq + r_) * XGW + hcol * 4];                 \
            *(f32x4*)dst_ = (f32x4){g0_[r_], g1_[r_], g2_[r_], g3_[r_]};          \
        } }

    XG_BURST(0, 0)          // xg for period 0
    __syncthreads();

    // initial xg for step (p=0,k=0): row (lq&1), buf 0
    f32x4 xg4 = *(const f32x4*)&xgb[0][(lq & 1) * XGW + hcol * 4];
    const f32x4 z4 = {0.f, 0.f, 0.f, 0.f};   // shared C-in for chain heads

#pragma unroll 1
    for (int p = 0; p < 25; ++p) {
        const int pe = p & 1;
#pragma unroll
        for (int k = 0; k < 8; ++k) {
            const int cur = k & 1;       // t = 8p+k, t&1 = k&1
            const int nxt = cur ^ 1;
            // A fragments: lr in {0,4} read real rows; others broadcast zero row
            const _Float16* hr = cur ? hpB : hpA;
            half8 a0 = *(const half8*)(hr);
            half8 a1 = *(const half8*)(hr + 32);
            half8 a2 = *(const half8*)(hr + 64);
            half8 a3 = *(const half8*)(hr + 96);
            // split-K chains: 8 accumulators, depth 2 (ILP 8)
            f32x4 ci0 = MFMA16(a0, bhh[0][0], z4);
            f32x4 ci1 = MFMA16(a2, bhh[0][2], z4);
            f32x4 cf0 = MFMA16(a0, bhh[1][0], z4);
            f32x4 cf1 = MFMA16(a2, bhh[1][2], z4);
            f32x4 cg0 = MFMA16(a0, bhh[2][0], z4);
            f32x4 cg1 = MFMA16(a2, bhh[2][2], z4);
            ci0 = MFMA16(a1, bhh[0][1], ci0);
            ci1 = MFMA16(a3, bhh[0][3], ci1);
            cf0 = MFMA16(a1, bhh[1][1], cf0);
            cf1 = MFMA16(a3, bhh[1][3], cf1);
            cg0 = MFMA16(a1, bhh[2][1], cg0);
            cg1 = MFMA16(a3, bhh[2][3], cg1);
            // early act front (all lanes; lanes with dead rows produce garbage)
            float gi = ci0[0] + ci1[0] + xg4[0];
            float gf = cf0[0] + cf1[0] + xg4[1];
            float gg = cg0[0] + cg1[0] + xg4[2];
            float si = sigm_fast(gi);
            float sf = sigm_fast(gf);
            float tg = tanh_fast(gg);
            float cnew = sf * cst + si * tg;
            // o-gate chains LAST (depth 2, ILP 2 + act front overlaps)
            f32x4 co0 = MFMA16(a0, bhh[3][0], z4);
            f32x4 co1 = MFMA16(a2, bhh[3][2], z4);
            co0 = MFMA16(a1, bhh[3][1], co0);
            co1 = MFMA16(a3, bhh[3][3], co1);
            if (k == 0 && p < 24) XG_BURST(p + 1, pe ^ 1)    // xg for period p+1
            // prefetch next step's xg (producer wrote >=1 barrier ago; at the
            // final step the value is simply unused)
            const int kn = (k + 1) & 7;
            const int pn = (k == 7) ? (pe ^ 1) : pe;
            f32x4 xgn = *(const f32x4*)&xgb[pn][(2*kn + (lq & 1)) * XGW + hcol * 4];
            // tail: sigm(go) || tanh(c) -> mul -> cvt -> write
            float hv = sigm_fast(co0[0] + co1[0] + xg4[3]) * tanh_fast(cnew);
            cst = cnew;
            if (l < 32) hz[2*nxt + lq][hcol] = (_Float16)hv;  // compact h write
            __syncthreads();
            xg4 = xgn;
        }
    }

    // FC epilogue: h_200 in hz rows 0,1 (t=199 wrote nxt=0)
    if (tid < 2 * CH) {
        const int s = tid >> 6, ch = tid & 63;
        const float* wf = W_fc + (size_t)ch * HID;
        float acc = b_fc[ch];
#pragma unroll
        for (int j8 = 0; j8 < 16; ++j8) {
            half8 hv = *(const half8*)&hz[s][8 * j8];
            float4 w0 = *(const float4*)(wf + 8 * j8);
            float4 w1 = *(const float4*)(wf + 8 * j8 + 4);
            acc += w0.x * (float)hv[0] + w0.y * (float)hv[1]
                 + w0.z * (float)hv[2] + w0.w * (float)hv[3]
                 + w1.x * (float)hv[4] + w1.y * (float)hv[5]
                 + w1.z * (float)hv[6] + w1.w * (float)hv[7];
        }
        out[(size_t)(n0 + s) * CH + ch] = acc;
    }
}

extern "C" void kernel_launch(void* const* d_in, const int* in_sizes, int n_in,
                              void* d_out, int out_size, void* d_ws, size_t ws_size,
                              hipStream_t stream) {
    (void)in_sizes; (void)n_in; (void)out_size; (void)d_ws; (void)ws_size;
    fused_lstm<<<NSEQ / 2, 512, 0, stream>>>(
        (const float*)d_in[0], (const float*)d_in[1], (const float*)d_in[2],
        (const float*)d_in[3], (const float*)d_in[4], (const float*)d_in[5],
        (const float*)d_in[6], (float*)d_out);
}

// Round 11
// 187.794 us; speedup vs baseline: 1.0364x; 1.0364x over previous
//
#include <hip/hip_runtime.h>

#define BATCH 16
#define CH    64
#define TLEN  200
#define NP    30
#define HID   128
#define NSEQ  (BATCH * NP)   // 480
#define HP    144            // hz row pitch in halves (288 B)
#define XP    72             // xlds per-seq row pitch in halves (144 B)
#define XGW   520            // xgb row pitch in floats (2080 B)

typedef _Float16 half8 __attribute__((ext_vector_type(8)));
typedef float    f32x4 __attribute__((ext_vector_type(4)));
typedef float    f32x2 __attribute__((ext_vector_type(2)));

// NaN/Inf-safe, clamp-free: exp->inf degrades gracefully through rcp.
__device__ __forceinline__ float sigm_fast(float x) {
    return __builtin_amdgcn_rcpf(1.0f + __expf(-x));
}
__device__ __forceinline__ float tanh_fast(float x) {
    return 1.0f - 2.0f * __builtin_amdgcn_rcpf(__expf(2.0f * x) + 1.0f);
}
__device__ __forceinline__ half8 cvt8(float4 a, float4 b) {
    return (half8){(_Float16)a.x,(_Float16)a.y,(_Float16)a.z,(_Float16)a.w,
                   (_Float16)b.x,(_Float16)b.y,(_Float16)b.z,(_Float16)b.w};
}

#define MFMA16(A,B,C) __builtin_amdgcn_mfma_f32_16x16x32_f16((A),(B),(C),0,0,0)

// ---------------------------------------------------------------------------
// Fused LSTM. 240 blocks (XCD-swizzled), 512 threads = 8 waves = 2 waves/SIMD.
// = r9 (best, 125us) + two surgical deltas:
//   - xg burst SPLIT by gate pair: {i,f} at k==0, {g,o} at k==1 (halves the
//     per-period long-pole step that the barrier propagates to all waves).
//   - next step's xg4 prefetched BEFORE the barrier (producer wrote it >=1
//     barrier earlier -> race-free; ~120cy LDS latency rides the barrier).
// Kept from r9: compact hz (rows 0-3 = h, row 4 = shared zero row ->
// broadcast A-reads), x fully LDS-resident (zero VMEM in loop), acc-major
// depth-4 chains with o-gate last, act on all lanes (write masked), setprio.
// ---------------------------------------------------------------------------
__global__ __launch_bounds__(512, 2) void fused_lstm(
    const float* __restrict__ x, const float* __restrict__ W_ih,
    const float* __restrict__ W_hh, const float* __restrict__ b_ih,
    const float* __restrict__ b_hh, const float* __restrict__ W_fc,
    const float* __restrict__ b_fc, float* __restrict__ out)
{
    const int tid = threadIdx.x;
    const int w  = tid >> 6;     // wave 0..7 -> owns gate sub-cols 16w+lr
    const int l  = tid & 63;
    const int lr = l & 15;
    const int lq = l >> 4;

    // XCD-chunked swizzle: XCD c gets pairs c*30..c*30+29 (= 2 full batches)
    const int blk  = blockIdx.x;
    const int pair = (blk & 7) * 30 + (blk >> 3);
    const int n0 = pair * 2;
    const int b0 = n0 / NP;
    const int p0 = n0 % NP;      // even -> both seqs share b0

    __shared__ __align__(16) _Float16 hz[5][HP];         // 1440 B; h compact + zero row
    __shared__ __align__(16) _Float16 xlds[TLEN][2][XP]; // 57600 B; ALL x, f16
    __shared__ __align__(16) float    xgb[2][16 * XGW];  // 66560 B; xg+bias, f32 C-layout

    // ---- W fragments in registers (loaded once) ----
    half8 bhh[4][4];   // W_hh, gate-type T, K-frag kt (K=128)
    half8 bih[4][2];   // W_ih, gate-type T, K-frag j  (K=64)
    float biasx[4];
#pragma unroll
    for (int T = 0; T < 4; ++T) {
        const int g = 128*T + 16*w + lr;
        const float* rh = W_hh + (size_t)g * HID;
        const float* ri = W_ih + (size_t)g * CH;
#pragma unroll
        for (int kt = 0; kt < 4; ++kt) {
            const int k0 = 32*kt + 8*lq;
            bhh[T][kt] = cvt8(*(const float4*)(rh + k0), *(const float4*)(rh + k0 + 4));
        }
#pragma unroll
        for (int j = 0; j < 2; ++j) {
            const int k0 = 32*j + 8*lq;
            bih[T][j] = cvt8(*(const float4*)(ri + k0), *(const float4*)(ri + k0 + 4));
        }
        biasx[T] = b_ih[g] + b_hh[g];
    }

    // zero hz: rows 0-3 = h_0 = 0; row 4 = permanent zero row (never written)
    if (tid < (5 * HP) / 2) ((unsigned*)hz)[tid] = 0u;

    // ---- prologue: stage ALL x for both seqs into LDS (one-time gather).
    for (int e = tid; e < CH * TLEN; e += 512) {
        const int t = e % TLEN, c = e / TLEN;
        const float* src = x + ((size_t)(b0 * CH + c) * TLEN + t) * NP + p0;
        float2 v = *(const float2*)src;
        xlds[t][0][c] = (_Float16)v.x;
        xlds[t][1][c] = (_Float16)v.y;
    }
    float cst = 0.f;                      // c-state: valid in lanes l<32
    const int hcol = 16*w + lr;
    // A-frag source rows: lr==0 -> seq0 row, lr==4 -> seq1 row, else ZERO row.
    const int hrow0 = (lr == 0) ? 0 : (lr == 4) ? 1 : 4;   // buf 0
    const int hrow1 = (lr == 0) ? 2 : (lr == 4) ? 3 : 4;   // buf 1
    const _Float16* hpA = &hz[hrow0][8 * lq];
    const _Float16* hpB = &hz[hrow1][8 * lq];
    __syncthreads();                      // hz + xlds resident

    // xg GEMM halves from resident xlds (rows t=8P..8P+7, both seqs).
    // A row lr -> (t = 8P + (lr>>1), seq = lr&1); C row (4lq+r) -> x-row 2δ+s.
    // HALF0 = gates {i,f} -> f32x2 at quad offset 0; HALF1 = {g,o} -> offset 2.
#define XG_HALF(P, TB, T0, T1, OFF) {                                             \
        const _Float16* xr_ = &xlds[8*(P) + (lr >> 1)][lr & 1][8*lq];             \
        half8 xf0_ = *(const half8*)xr_;                                          \
        half8 xf1_ = *(const half8*)(xr_ + 32);                                   \
        f32x4 ga_ = {biasx[T0], biasx[T0], biasx[T0], biasx[T0]};                 \
        f32x4 gb_ = {biasx[T1], biasx[T1], biasx[T1], biasx[T1]};                 \
        ga_ = MFMA16(xf0_, bih[T0][0], ga_); ga_ = MFMA16(xf1_, bih[T0][1], ga_); \
        gb_ = MFMA16(xf0_, bih[T1][0], gb_); gb_ = MFMA16(xf1_, bih[T1][1], gb_); \
        _Pragma("unroll") for (int r_ = 0; r_ < 4; ++r_) {                        \
            float* dst_ = &xgb[TB][(4*lq + r_) * XGW + hcol * 4 + (OFF)];         \
            *(f32x2*)dst_ = (f32x2){ga_[r_], gb_[r_]};                            \
        } }

    XG_HALF(0, 0, 0, 1, 0)   // period-0 xg, gates i,f
    XG_HALF(0, 0, 2, 3, 2)   // period-0 xg, gates g,o
    __syncthreads();

    // xg for step (p=0,k=0): row (lq&1), buf 0
    f32x4 xg4 = *(const f32x4*)&xgb[0][(lq & 1) * XGW + hcol * 4];

#pragma unroll 1
    for (int p = 0; p < 25; ++p) {
        const int pe = p & 1;
#pragma unroll
        for (int k = 0; k < 8; ++k) {
            const int cur = k & 1;       // t = 8p+k, t&1 = k&1
            const int nxt = cur ^ 1;
            // A fragments: lr in {0,4} read real rows; others broadcast zero row
            const _Float16* hr = cur ? hpB : hpA;
            half8 a0 = *(const half8*)(hr);
            half8 a1 = *(const half8*)(hr + 32);
            half8 a2 = *(const half8*)(hr + 64);
            half8 a3 = *(const half8*)(hr + 96);
            f32x4 zz = {0.f, 0.f, 0.f, 0.f};
            f32x4 ci = zz, cf = zz, cg = zz, co = zz;
            __builtin_amdgcn_s_setprio(1);
            // acc-major chains: i,f,g complete EARLY
            ci = MFMA16(a0, bhh[0][0], ci); ci = MFMA16(a1, bhh[0][1], ci);
            ci = MFMA16(a2, bhh[0][2], ci); ci = MFMA16(a3, bhh[0][3], ci);
            cf = MFMA16(a0, bhh[1][0], cf); cf = MFMA16(a1, bhh[1][1], cf);
            cf = MFMA16(a2, bhh[1][2], cf); cf = MFMA16(a3, bhh[1][3], cf);
            cg = MFMA16(a0, bhh[2][0], cg); cg = MFMA16(a1, bhh[2][1], cg);
            cg = MFMA16(a2, bhh[2][2], cg); cg = MFMA16(a3, bhh[2][3], cg);
            // early act front (all lanes; dead-row lanes produce garbage)
            float si = sigm_fast(ci[0] + xg4[0]);
            float sf = sigm_fast(cf[0] + xg4[1]);
            float tg = tanh_fast(cg[0] + xg4[2]);
            float cnew = sf * cst + si * tg;
            // o-gate chain LAST
            co = MFMA16(a0, bhh[3][0], co); co = MFMA16(a1, bhh[3][1], co);
            co = MFMA16(a2, bhh[3][2], co); co = MFMA16(a3, bhh[3][3], co);
            __builtin_amdgcn_s_setprio(0);
            // split xg burst for period p+1 (amortized off the long-pole)
            if (p < 24) {
                if (k == 0) XG_HALF(p + 1, pe ^ 1, 0, 1, 0)
                if (k == 1) XG_HALF(p + 1, pe ^ 1, 2, 3, 2)
            }
            // tail: sigm(go) || tanh(c) -> mul -> cvt -> write
            float hv = sigm_fast(co[0] + xg4[3]) * tanh_fast(cnew);
            cst = cnew;
            if (l < 32) hz[2*nxt + lq][hcol] = (_Float16)hv;  // compact h write
            // prefetch next step's xg BEFORE the barrier (written >=1 barrier
            // ago -> race-free; final-step value simply unused)
            const int kn = (k + 1) & 7;
            const int pn = (k == 7) ? (pe ^ 1) : pe;
            f32x4 xgn = *(const f32x4*)&xgb[pn][(2*kn + (lq & 1)) * XGW + hcol * 4];
            __syncthreads();
            xg4 = xgn;
        }
    }

    // FC epilogue: h_200 in hz rows 0,1 (t=199 wrote nxt=0)
    if (tid < 2 * CH) {
        const int s = tid >> 6, ch = tid & 63;
        const float* wf = W_fc + (size_t)ch * HID;
        float acc = b_fc[ch];
#pragma unroll
        for (int j8 = 0; j8 < 16; ++j8) {
            half8 hv = *(const half8*)&hz[s][8 * j8];
            float4 w0 = *(const float4*)(wf + 8 * j8);
            float4 w1 = *(const float4*)(wf + 8 * j8 + 4);
            acc += w0.x * (float)hv[0] + w0.y * (float)hv[1]
                 + w0.z * (float)hv[2] + w0.w * (float)hv[3]
                 + w1.x * (float)hv[4] + w1.y * (float)hv[5]
                 + w1.z * (float)hv[6] + w1.w * (float)hv[7];
        }
        out[(size_t)(n0 + s) * CH + ch] = acc;
    }
}

extern "C" void kernel_launch(void* const* d_in, const int* in_sizes, int n_in,
                              void* d_out, int out_size, void* d_ws, size_t ws_size,
                              hipStream_t stream) {
    (void)in_sizes; (void)n_in; (void)out_size; (void)d_ws; (void)ws_size;
    fused_lstm<<<NSEQ / 2, 512, 0, stream>>>(
        (const float*)d_in[0], (const float*)d_in[1], (const float*)d_in[2],
        (const float*)d_in[3], (const float*)d_in[4], (const float*)d_in[5],
        (const float*)d_in[6], (float*)d_out);
}